// Round 4
// baseline (268.265 us; speedup 1.0000x reference)
//
#include <hip/hip_runtime.h>
#include <hip/hip_bf16.h>

using short8  = __attribute__((ext_vector_type(8))) short;
using f32x4   = __attribute__((ext_vector_type(4))) float;

#if __has_builtin(__builtin_amdgcn_exp2f)
#define EXP2(x) __builtin_amdgcn_exp2f(x)
#else
#define EXP2(x) __expf(0.6931471805599453f*(x))
#endif

__device__ __forceinline__ unsigned short f2bf(float x){
  union { float f; unsigned u; } c; c.f = x;
  unsigned u = c.u + 0x7FFFu + ((c.u >> 16) & 1u);
  return (unsigned short)(u >> 16);
}

__device__ __forceinline__ unsigned pack_bf16_rn(float a, float b){
  __hip_bfloat162 t = __float22bfloat162_rn(make_float2(a, b));
  unsigned u; __builtin_memcpy(&u, &t, 4);
  return u;
}

// ---------------- fused prep: dtype conversions + mask bit-pack ----------------
// bid < 8192: bf16 conversions (X, Wq*log2e/8, Wk, Wv, Wo)
// bid in [8192,12288): mask -> 1 bit/key via ballot. Row (b*2048+q) -> 32 u64 words.
__global__ __launch_bounds__(256) void prep(const float* __restrict__ X, const int* __restrict__ Mk,
                                            const float* __restrict__ Wq, const float* __restrict__ Wk,
                                            const float* __restrict__ Wv, const float* __restrict__ Wo,
                                            unsigned short* __restrict__ Xb, unsigned short* __restrict__ Wqkv,
                                            unsigned short* __restrict__ Wob, unsigned long long* __restrict__ Mbits)
{
  const int bid = blockIdx.x, tid = threadIdx.x;
  if (bid < 8192){
    const float* src; unsigned short* dst; float scale; int i;
    if (bid < 4096)      { src = X;  dst = Xb;             scale = 1.0f;          i = bid*1024 + tid*4; }
    else if (bid < 5120) { src = Wq; dst = Wqkv;           scale = 0.18033688f;   i = (bid-4096)*1024 + tid*4; } // 1/8 * log2(e)
    else if (bid < 6144) { src = Wk; dst = Wqkv + 1048576; scale = 1.0f;          i = (bid-5120)*1024 + tid*4; }
    else if (bid < 7168) { src = Wv; dst = Wqkv + 2097152; scale = 1.0f;          i = (bid-6144)*1024 + tid*4; }
    else                 { src = Wo; dst = Wob;            scale = 1.0f;          i = (bid-7168)*1024 + tid*4; }
    float4 v = *(const float4*)(src + i);
    ushort4 o;
    o.x = f2bf(v.x * scale); o.y = f2bf(v.y * scale);
    o.z = f2bf(v.z * scale); o.w = f2bf(v.w * scale);
    *(ushort4*)(dst + i) = o;
  } else {
    // one block per mask row; wave w covers keys [w*512, w*512+512)
    int row = bid - 8192;                       // 0..4095 = b*2048+q
    const int* src = Mk + (size_t)row * 2048;
    unsigned long long* dst = Mbits + (size_t)row * 32;
    int w = tid >> 6, l = tid & 63;
    #pragma unroll
    for (int p = 0; p < 8; p++){
      int v = src[w*512 + p*64 + l];            // coalesced 256B per ballot
      unsigned long long bm = __ballot(v != 0);
      if (l == 0) dst[w*8 + p] = bm;            // bit l of word = key w*512+p*64+l
    }
  }
}

// ---------------- async global->LDS, width 16 ----------------
__device__ __forceinline__ void stage16(const unsigned short* g, unsigned short* l){
  __builtin_amdgcn_global_load_lds(
      (const __attribute__((address_space(1))) void*)g,
      (__attribute__((address_space(3))) void*)l, 16, 0, 0);
}

// ---------------- gemm1: QKV = Xb * Wqkv^T; V-blocks write Vg transposed ----------
__global__ __launch_bounds__(256) void gemm_qkv(const unsigned short* __restrict__ A,
                                                const unsigned short* __restrict__ B,
                                                unsigned short* __restrict__ C,
                                                unsigned short* __restrict__ Vg)
{
  __shared__ unsigned short As[128*32];
  __shared__ unsigned short Bs[128*32];
  const int tid = threadIdx.x;
  const int wave = tid >> 6, lane = tid & 63, l16 = lane & 15, quad = lane >> 4;
  const int id = blockIdx.x, xcd = id & 7, m = id >> 3;
  const int bm = (m / 3) * 128, bn = (xcd * 3 + (m % 3)) * 128;
  const int wm = (wave >> 1) * 64, wn = (wave & 1) * 64;
  const int K = 1024;

  f32x4 acc[4][4] = {};
  for (int k0 = 0; k0 < K; k0 += 32){
    #pragma unroll
    for (int c = 0; c < 2; c++){
      int idx = c * 256 + tid;
      int row = idx >> 2, g = (idx & 3) * 8;
      stage16(A + (size_t)(bm + row) * K + k0 + g, &As[idx * 8]);
      stage16(B + (size_t)(bn + row) * K + k0 + g, &Bs[idx * 8]);
    }
    __syncthreads();
    short8 af[4], bf[4];
    #pragma unroll
    for (int i = 0; i < 4; i++) af[i] = *(const short8*)&As[(wm + i*16 + l16)*32 + quad*8];
    #pragma unroll
    for (int j = 0; j < 4; j++) bf[j] = *(const short8*)&Bs[(wn + j*16 + l16)*32 + quad*8];
    #pragma unroll
    for (int i = 0; i < 4; i++)
      #pragma unroll
      for (int j = 0; j < 4; j++)
        acc[i][j] = __builtin_amdgcn_mfma_f32_16x16x32_bf16(af[i], bf[j], acc[i][j], 0, 0, 0);
    __syncthreads();
  }

  if (bn < 2048){
    #pragma unroll
    for (int i = 0; i < 4; i++){
      int mrow = bm + wm + i*16 + quad*4;
      #pragma unroll
      for (int j = 0; j < 4; j++){
        int ncol = bn + wn + j*16 + l16;
        #pragma unroll
        for (int r = 0; r < 4; r++)
          C[(size_t)(mrow + r) * 3072 + ncol] = f2bf(acc[i][j][r]);
      }
    }
  } else {
    // write V transposed: Vg[bh][d][s], 4 s-consecutive bf16 per lane (8B store)
    #pragma unroll
    for (int i = 0; i < 4; i++){
      int srow = bm + wm + i*16 + quad*4;
      int b = srow >> 11, s = srow & 2047;
      #pragma unroll
      for (int j = 0; j < 4; j++){
        int c = bn - 2048 + wn + j*16 + l16;
        int h = c >> 6, d = c & 63;
        ushort4 o;
        o.x = f2bf(acc[i][j][0]); o.y = f2bf(acc[i][j][1]);
        o.z = f2bf(acc[i][j][2]); o.w = f2bf(acc[i][j][3]);
        *(ushort4*)&Vg[((size_t)(b*16 + h)*64 + d) * 2048 + s] = o;
      }
    }
  }
}

// ---------------- gemm2: out = Ob * Wob^T (f32 out), 128x64 tiles, XCD-swizzled ----
__global__ __launch_bounds__(256) void gemm_out(const unsigned short* __restrict__ A,
                                                const unsigned short* __restrict__ B,
                                                float* __restrict__ Cf)
{
  __shared__ unsigned short As[128*32];
  __shared__ unsigned short Bs[64*32];
  const int tid = threadIdx.x;
  const int wave = tid >> 6, lane = tid & 63, l16 = lane & 15, quad = lane >> 4;
  const int id = blockIdx.x, xcd = id & 7, m = id >> 3;
  const int bm = (m >> 1) * 128, bn = (xcd * 2 + (m & 1)) * 64;
  const int wm = (wave >> 1) * 64, wn = (wave & 1) * 32;
  const int K = 1024, N = 1024;

  f32x4 acc[4][2] = {};
  for (int k0 = 0; k0 < K; k0 += 32){
    #pragma unroll
    for (int c = 0; c < 2; c++){
      int idx = c * 256 + tid;
      int row = idx >> 2, g = (idx & 3) * 8;
      stage16(A + (size_t)(bm + row) * K + k0 + g, &As[idx * 8]);
    }
    stage16(B + (size_t)(bn + (tid >> 2)) * K + k0 + (tid & 3) * 8, &Bs[tid * 8]);
    __syncthreads();
    short8 af[4], bf[2];
    #pragma unroll
    for (int i = 0; i < 4; i++) af[i] = *(const short8*)&As[(wm + i*16 + l16)*32 + quad*8];
    #pragma unroll
    for (int j = 0; j < 2; j++) bf[j] = *(const short8*)&Bs[(wn + j*16 + l16)*32 + quad*8];
    #pragma unroll
    for (int i = 0; i < 4; i++)
      #pragma unroll
      for (int j = 0; j < 2; j++)
        acc[i][j] = __builtin_amdgcn_mfma_f32_16x16x32_bf16(af[i], bf[j], acc[i][j], 0, 0, 0);
    __syncthreads();
  }
  #pragma unroll
  for (int i = 0; i < 4; i++){
    int mrow = bm + wm + i*16 + quad*4;
    #pragma unroll
    for (int j = 0; j < 2; j++){
      int ncol = bn + wn + j*16 + l16;
      #pragma unroll
      for (int r = 0; r < 4; r++)
        Cf[(size_t)(mrow + r) * N + ncol] = acc[i][j][r];
    }
  }
}

// ---------------- attention: LDS-P aliased onto dead K buffer, 32 KB LDS ---------
// Wave w: computes S^T strip (its 16 keys x 64 q), exp+cndmask+packs, writes P^T
// to LDS; then owns O^T d-strip [w*16, w*16+16) over ALL 64 keys of the chunk.
// LDS: Ks 2x8KB + Vt 2x8KB = 32768 B. P^T ALIASES Ks[buf] (dead after kf loads;
// barrier A2 guards the handoff). 160KiB/32KB = 5 blocks/CU capacity -> all 4
// grid blocks/CU co-resident (round-3 showed 40960B capped residency at 3,
// leaving a serial 4th-block tail on this latency-bound kernel).
// DMA hazard audit: c+1 DMAs target Ks[buf^1] (disjoint from P=Ks[buf]);
// c+2 DMAs target Ks[buf] but are issued after syncthreads drains P reads.
__global__ __launch_bounds__(256, 4) void attn(const unsigned short* __restrict__ QKV,
                                               const unsigned short* __restrict__ Vg,
                                               const unsigned short* __restrict__ mask16,
                                               unsigned short* __restrict__ O)
{
  __shared__ char smem[32768];
  unsigned short* Ks = (unsigned short*)smem;            // [2][64*64] 16 KB, xor-swizzled 16B blocks
  unsigned short* Vt = (unsigned short*)(smem + 16384);  // [2][64*64] 16 KB, [d][key] xor-swizzled
  float* lsums = (float*)smem;                           // epilogue alias over dead Ks[0]: [q][4] f32

  const int tid = threadIdx.x, wave = tid >> 6, lane = tid & 63;
  const int l16 = lane & 15, quad = lane >> 4;
  const int id = blockIdx.x;
  const int xcd = id & 7, m = id >> 3;         // round-robin XCD assumption
  const int bh = xcd * 4 + (m >> 5);           // 4 bh per XCD (K/V stay in this XCD's L2)
  const int qblk = (m & 31) * 64;
  const int b = bh >> 4, h = bh & 15;
  const unsigned short* Qg  = QKV + (size_t)b * 2048 * 3072 + h * 64;
  const unsigned short* Kg  = Qg + 1024;
  const unsigned short* Vgb = Vg + (size_t)bh * 64 * 2048;

  // per-nt bitmask row pointers: row = b*2048 + qblk + nt*16 + l16, this wave's
  // 16-key group at ushort offset c*4 + wave
  const unsigned short* mp[4];
  #pragma unroll
  for (int nt = 0; nt < 4; nt++)
    mp[nt] = mask16 + (size_t)(b*2048 + qblk + nt*16 + l16) * 128 + wave;

  // Q B-fragments resident in registers: B[n=q=l16][k=d=ks*32+quad*8+j]
  short8 qf[4][2];
  #pragma unroll
  for (int nt = 0; nt < 4; nt++)
    #pragma unroll
    for (int ks = 0; ks < 2; ks++)
      qf[nt][ks] = *(const short8*)(Qg + (size_t)(qblk + nt*16 + l16) * 3072 + ks*32 + quad*8);

  f32x4 oacc[4] = {};               // O^T strip: d = wave*16+quad*4+r, q = nt*16+l16
  float plsum[4] = {0.f, 0.f, 0.f, 0.f};
  const int sw = l16 & 7;

  // prologue: stage chunk 0 into buffer 0; load chunk-0 mask bits
  #pragma unroll
  for (int it = 0; it < 2; it++){
    int s = it * 256 + tid;
    int row = s >> 3, bg = (s & 7) ^ (row & 7);
    stage16(Kg + (size_t)row * 3072 + bg * 8, Ks + s * 8);
    stage16(Vgb + (size_t)row * 2048 + bg * 8, Vt + s * 8);
  }
  unsigned mcur[4], mnxt[4] = {0u, 0u, 0u, 0u};
  #pragma unroll
  for (int nt = 0; nt < 4; nt++) mcur[nt] = mp[nt][0];

  for (int c = 0; c < 32; c++){
    const int j0 = c * 64;
    const int buf = (c & 1) * 4096;
    unsigned short* Ps = Ks + buf;   // P^T aliases the K buffer consumed this chunk
    __syncthreads();   // A: chunk-c DMAs + mask regs landed (vmcnt), prev PV's P reads done (lgkm)

    // issue next chunk's DMAs + mask prefetch; they fly through QK+PV, drained at next A
    if (c < 31){
      const int nj = j0 + 64, nbuf = ((c + 1) & 1) * 4096;
      #pragma unroll
      for (int it = 0; it < 2; it++){
        int s = it * 256 + tid;
        int row = s >> 3, bg = (s & 7) ^ (row & 7);
        stage16(Kg + (size_t)(nj + row) * 3072 + bg * 8, Ks + nbuf + s * 8);
        stage16(Vgb + (size_t)row * 2048 + nj + bg * 8, Vt + nbuf + s * 8);
      }
      #pragma unroll
      for (int nt = 0; nt < 4; nt++) mnxt[nt] = mp[nt][(c + 1) * 4];
    }

    // load this wave's K fragments; then barrier A2 before P writes clobber Ks[buf]
    short8 kf0 = *(const short8*)&Ks[buf + (wave*16 + l16) * 64 + ((0 + quad) ^ sw) * 8];
    short8 kf1 = *(const short8*)&Ks[buf + (wave*16 + l16) * 64 + ((4 + quad) ^ sw) * 8];
    __asm__ volatile("s_waitcnt lgkmcnt(0)" ::: "memory");   // kf in regs (all waves)
    __builtin_amdgcn_s_barrier();                            // no vmcnt drain: DMAs keep flying
    __builtin_amdgcn_sched_barrier(0);

    // S^T = K * Q^T for this wave's 16 keys; exp; mask-select 1.0; pack; P^T to LDS
    #pragma unroll
    for (int nt = 0; nt < 4; nt++){
      f32x4 a = {0.f, 0.f, 0.f, 0.f};
      __builtin_amdgcn_s_setprio(1);
      a = __builtin_amdgcn_mfma_f32_16x16x32_bf16(kf0, qf[nt][0], a, 0, 0, 0);
      a = __builtin_amdgcn_mfma_f32_16x16x32_bf16(kf1, qf[nt][1], a, 0, 0, 0);
      __builtin_amdgcn_s_setprio(0);
      // scores in log2 domain (log2e folded into Wq); masked -> select 1.0 (=exp(-1e-9))
      float p0 = EXP2(a[0]);
      float p1 = EXP2(a[1]);
      float p2 = EXP2(a[2]);
      float p3 = EXP2(a[3]);
      unsigned mq = mcur[nt] >> (quad << 2);
      p0 = (mq & 1u) ? p0 : 1.0f;
      p1 = (mq & 2u) ? p1 : 1.0f;
      p2 = (mq & 4u) ? p2 : 1.0f;
      p3 = (mq & 8u) ? p3 : 1.0f;
      plsum[nt] += (p0 + p1) + (p2 + p3);
      uint2 st; st.x = pack_bf16_rn(p0, p1); st.y = pack_bf16_rn(p2, p3);
      // Ps[q = nt*16+l16][keys wave*16+quad*4 .. +3], xor-swizzled 16B blocks
      *(uint2*)&Ps[(nt*16 + l16) * 64 + ((wave*2 + (quad >> 1)) ^ sw) * 8 + (quad & 1) * 4] = st;
    }

    // B: P^T ready. LDS-only wait + raw barrier (does NOT drain the c+1 DMAs).
    __asm__ volatile("s_waitcnt lgkmcnt(0)" ::: "memory");
    __builtin_amdgcn_s_barrier();
    __builtin_amdgcn_sched_barrier(0);

    // O^T strip += V^T * P^T over all 64 keys: 2 k-steps of 32 (K=32 MFMA, b128 reads)
    #pragma unroll
    for (int kk = 0; kk < 2; kk++){
      short8 vfrag = *(const short8*)&Vt[buf + (wave*16 + l16) * 64 + ((kk*4 + quad) ^ sw) * 8];
      short8 pf[4];
      #pragma unroll
      for (int nt = 0; nt < 4; nt++)
        pf[nt] = *(const short8*)&Ps[(nt*16 + l16) * 64 + ((kk*4 + quad) ^ sw) * 8];
      __builtin_amdgcn_s_setprio(1);
      #pragma unroll
      for (int nt = 0; nt < 4; nt++)
        oacc[nt] = __builtin_amdgcn_mfma_f32_16x16x32_bf16(vfrag, pf[nt], oacc[nt], 0, 0, 0);
      __builtin_amdgcn_s_setprio(0);
    }

    #pragma unroll
    for (int nt = 0; nt < 4; nt++) mcur[nt] = mnxt[nt];
  }

  // ---- epilogue: lsum cross-wave reduce via LDS; disjoint O store (no O reduce) ----
  float lw[4];
  #pragma unroll
  for (int nt = 0; nt < 4; nt++){
    float v = plsum[nt];
    v += __shfl_xor(v, 16);
    v += __shfl_xor(v, 32);
    lw[nt] = v;
  }
  __syncthreads();                   // PV ds_reads done; last P is at Ks+4096 -> Ks[0] dead
  if (quad == 0){
    #pragma unroll
    for (int nt = 0; nt < 4; nt++) lsums[(nt*16 + l16) * 4 + wave] = lw[nt];
  }
  __syncthreads();
  float linv[4];
  #pragma unroll
  for (int nt = 0; nt < 4; nt++){
    f32x4 ls = *(const f32x4*)&lsums[(nt*16 + l16) * 4];
    linv[nt] = 1.0f / (ls[0] + ls[1] + ls[2] + ls[3]);
  }
  #pragma unroll
  for (int nt = 0; nt < 4; nt++){
    f32x4 t = oacc[nt];
    unsigned u0 = pack_bf16_rn(t[0] * linv[nt], t[1] * linv[nt]);
    unsigned u1 = pack_bf16_rn(t[2] * linv[nt], t[3] * linv[nt]);
    uint2 st; st.x = u0; st.y = u1;
    *(uint2*)&O[(size_t)(b*2048 + qblk + nt*16 + l16) * 1024 + h*64 + wave*16 + quad*4] = st;
  }
}

// ---------------- launch ----------------
extern "C" void kernel_launch(void* const* d_in, const int* in_sizes, int n_in,
                              void* d_out, int out_size, void* d_ws, size_t ws_size,
                              hipStream_t stream)
{
  const float* X  = (const float*)d_in[0];
  const int*   Mk = (const int*)d_in[1];
  const float* Wq = (const float*)d_in[2];
  const float* Wk = (const float*)d_in[3];
  const float* Wv = (const float*)d_in[4];
  const float* Wo = (const float*)d_in[5];
  float* out = (float*)d_out;

  char* ws = (char*)d_ws;
  unsigned short* Xb   = (unsigned short*)(ws + 0);          //  8 MB  [4096][1024]
  unsigned short* Wqkv = (unsigned short*)(ws + 8388608);    //  6 MB  [3072][1024]
  unsigned short* Wob  = (unsigned short*)(ws + 14680064);   //  2 MB  [1024][1024]
  unsigned short* QKV  = (unsigned short*)(ws + 16777216);   // 24 MB  [4096][3072] (V cols unused)
  unsigned short* Ob   = (unsigned short*)(ws + 41943040);   //  8 MB  [4096][1024]
  unsigned long long* Mb = (unsigned long long*)(ws + 50331648); // 1 MB [4096][32] u64 bitmask
  unsigned short* Vg   = (unsigned short*)(ws + 58720256);   //  8 MB  [32][64][2048]

  prep<<<12288, 256, 0, stream>>>(X, Mk, Wq, Wk, Wv, Wo, Xb, Wqkv, Wob, Mb);
  gemm_qkv<<<768, 256, 0, stream>>>(Xb, Wqkv, QKV, Vg);
  attn<<<1024, 256, 0, stream>>>(QKV, Vg, (const unsigned short*)Mb, Ob);
  gemm_out<<<512, 256, 0, stream>>>(Ob, Wob, out);
}

// Round 6
// 267.549 us; speedup vs baseline: 1.0027x; 1.0027x over previous
//
#include <hip/hip_runtime.h>
#include <hip/hip_bf16.h>

using short8  = __attribute__((ext_vector_type(8))) short;
using f32x4   = __attribute__((ext_vector_type(4))) float;

#if __has_builtin(__builtin_amdgcn_exp2f)
#define EXP2(x) __builtin_amdgcn_exp2f(x)
#else
#define EXP2(x) __expf(0.6931471805599453f*(x))
#endif

__device__ __forceinline__ unsigned short f2bf(float x){
  union { float f; unsigned u; } c; c.f = x;
  unsigned u = c.u + 0x7FFFu + ((c.u >> 16) & 1u);
  return (unsigned short)(u >> 16);
}

__device__ __forceinline__ unsigned pack_bf16_rn(float a, float b){
  __hip_bfloat162 t = __float22bfloat162_rn(make_float2(a, b));
  unsigned u; __builtin_memcpy(&u, &t, 4);
  return u;
}

// ---------------- fused prep: dtype conversions + mask bit-pack ----------------
__global__ __launch_bounds__(256) void prep(const float* __restrict__ X, const int* __restrict__ Mk,
                                            const float* __restrict__ Wq, const float* __restrict__ Wk,
                                            const float* __restrict__ Wv, const float* __restrict__ Wo,
                                            unsigned short* __restrict__ Xb, unsigned short* __restrict__ Wqkv,
                                            unsigned short* __restrict__ Wob, unsigned long long* __restrict__ Mbits)
{
  const int bid = blockIdx.x, tid = threadIdx.x;
  if (bid < 8192){
    const float* src; unsigned short* dst; float scale; int i;
    if (bid < 4096)      { src = X;  dst = Xb;             scale = 1.0f;          i = bid*1024 + tid*4; }
    else if (bid < 5120) { src = Wq; dst = Wqkv;           scale = 0.18033688f;   i = (bid-4096)*1024 + tid*4; } // 1/8 * log2(e)
    else if (bid < 6144) { src = Wk; dst = Wqkv + 1048576; scale = 1.0f;          i = (bid-5120)*1024 + tid*4; }
    else if (bid < 7168) { src = Wv; dst = Wqkv + 2097152; scale = 1.0f;          i = (bid-6144)*1024 + tid*4; }
    else                 { src = Wo; dst = Wob;            scale = 1.0f;          i = (bid-7168)*1024 + tid*4; }
    float4 v = *(const float4*)(src + i);
    ushort4 o;
    o.x = f2bf(v.x * scale); o.y = f2bf(v.y * scale);
    o.z = f2bf(v.z * scale); o.w = f2bf(v.w * scale);
    *(ushort4*)(dst + i) = o;
  } else {
    int row = bid - 8192;                       // 0..4095 = b*2048+q
    const int* src = Mk + (size_t)row * 2048;
    unsigned long long* dst = Mbits + (size_t)row * 32;
    int w = tid >> 6, l = tid & 63;
    #pragma unroll
    for (int p = 0; p < 8; p++){
      int v = src[w*512 + p*64 + l];
      unsigned long long bm = __ballot(v != 0);
      if (l == 0) dst[w*8 + p] = bm;
    }
  }
}

// ---------------- async global->LDS, width 16 ----------------
__device__ __forceinline__ void stage16(const unsigned short* g, unsigned short* l){
  __builtin_amdgcn_global_load_lds(
      (const __attribute__((address_space(1))) void*)g,
      (__attribute__((address_space(3))) void*)l, 16, 0, 0);
}

// ---------------- gemm1: QKV = Xb * Wqkv^T; V-blocks write Vg transposed ----------
__global__ __launch_bounds__(256) void gemm_qkv(const unsigned short* __restrict__ A,
                                                const unsigned short* __restrict__ B,
                                                unsigned short* __restrict__ C,
                                                unsigned short* __restrict__ Vg)
{
  __shared__ unsigned short As[128*32];
  __shared__ unsigned short Bs[128*32];
  const int tid = threadIdx.x;
  const int wave = tid >> 6, lane = tid & 63, l16 = lane & 15, quad = lane >> 4;
  const int id = blockIdx.x, xcd = id & 7, m = id >> 3;
  const int bm = (m / 3) * 128, bn = (xcd * 3 + (m % 3)) * 128;
  const int wm = (wave >> 1) * 64, wn = (wave & 1) * 64;
  const int K = 1024;

  f32x4 acc[4][4] = {};
  for (int k0 = 0; k0 < K; k0 += 32){
    #pragma unroll
    for (int c = 0; c < 2; c++){
      int idx = c * 256 + tid;
      int row = idx >> 2, g = (idx & 3) * 8;
      stage16(A + (size_t)(bm + row) * K + k0 + g, &As[idx * 8]);
      stage16(B + (size_t)(bn + row) * K + k0 + g, &Bs[idx * 8]);
    }
    __syncthreads();
    short8 af[4], bf[4];
    #pragma unroll
    for (int i = 0; i < 4; i++) af[i] = *(const short8*)&As[(wm + i*16 + l16)*32 + quad*8];
    #pragma unroll
    for (int j = 0; j < 4; j++) bf[j] = *(const short8*)&Bs[(wn + j*16 + l16)*32 + quad*8];
    #pragma unroll
    for (int i = 0; i < 4; i++)
      #pragma unroll
      for (int j = 0; j < 4; j++)
        acc[i][j] = __builtin_amdgcn_mfma_f32_16x16x32_bf16(af[i], bf[j], acc[i][j], 0, 0, 0);
    __syncthreads();
  }

  if (bn < 2048){
    #pragma unroll
    for (int i = 0; i < 4; i++){
      int mrow = bm + wm + i*16 + quad*4;
      #pragma unroll
      for (int j = 0; j < 4; j++){
        int ncol = bn + wn + j*16 + l16;
        #pragma unroll
        for (int r = 0; r < 4; r++)
          C[(size_t)(mrow + r) * 3072 + ncol] = f2bf(acc[i][j][r]);
      }
    }
  } else {
    #pragma unroll
    for (int i = 0; i < 4; i++){
      int srow = bm + wm + i*16 + quad*4;
      int b = srow >> 11, s = srow & 2047;
      #pragma unroll
      for (int j = 0; j < 4; j++){
        int c = bn - 2048 + wn + j*16 + l16;
        int h = c >> 6, d = c & 63;
        ushort4 o;
        o.x = f2bf(acc[i][j][0]); o.y = f2bf(acc[i][j][1]);
        o.z = f2bf(acc[i][j][2]); o.w = f2bf(acc[i][j][3]);
        *(ushort4*)&Vg[((size_t)(b*16 + h)*64 + d) * 2048 + s] = o;
      }
    }
  }
}

// ---------------- gemm2: out = Ob * Wob^T (f32 out), 128x64 tiles, XCD-swizzled ----
__global__ __launch_bounds__(256) void gemm_out(const unsigned short* __restrict__ A,
                                                const unsigned short* __restrict__ B,
                                                float* __restrict__ Cf)
{
  __shared__ unsigned short As[128*32];
  __shared__ unsigned short Bs[64*32];
  const int tid = threadIdx.x;
  const int wave = tid >> 6, lane = tid & 63, l16 = lane & 15, quad = lane >> 4;
  const int id = blockIdx.x, xcd = id & 7, m = id >> 3;
  const int bm = (m >> 1) * 128, bn = (xcd * 2 + (m & 1)) * 64;
  const int wm = (wave >> 1) * 64, wn = (wave & 1) * 32;
  const int K = 1024, N = 1024;

  f32x4 acc[4][2] = {};
  for (int k0 = 0; k0 < K; k0 += 32){
    #pragma unroll
    for (int c = 0; c < 2; c++){
      int idx = c * 256 + tid;
      int row = idx >> 2, g = (idx & 3) * 8;
      stage16(A + (size_t)(bm + row) * K + k0 + g, &As[idx * 8]);
    }
    stage16(B + (size_t)(bn + (tid >> 2)) * K + k0 + (tid & 3) * 8, &Bs[tid * 8]);
    __syncthreads();
    short8 af[4], bf[2];
    #pragma unroll
    for (int i = 0; i < 4; i++) af[i] = *(const short8*)&As[(wm + i*16 + l16)*32 + quad*8];
    #pragma unroll
    for (int j = 0; j < 2; j++) bf[j] = *(const short8*)&Bs[(wn + j*16 + l16)*32 + quad*8];
    #pragma unroll
    for (int i = 0; i < 4; i++)
      #pragma unroll
      for (int j = 0; j < 2; j++)
        acc[i][j] = __builtin_amdgcn_mfma_f32_16x16x32_bf16(af[i], bf[j], acc[i][j], 0, 0, 0);
    __syncthreads();
  }
  #pragma unroll
  for (int i = 0; i < 4; i++){
    int mrow = bm + wm + i*16 + quad*4;
    #pragma unroll
    for (int j = 0; j < 2; j++){
      int ncol = bn + wn + j*16 + l16;
      #pragma unroll
      for (int r = 0; r < 4; r++)
        Cf[(size_t)(mrow + r) * N + ncol] = acc[i][j][r];
    }
  }
}

// ---------------- attention: cross-chunk pipelined QK_c || PV_{c-1} ---------
// Rounds 2-4 showed the wall is invariant to residency (occupancy pinned ~35%,
// dur ~100us): blocks march in barrier-locked phases and the serial chain
// {sync->kf read->QK->exp->sync->pf read->PV} exposes all LDS latency.
// Fix: iteration c computes QK of chunk c AND PV of chunk c-1 (independent
// data). P gets its own double buffer Pb[2]: PV reads slot (c-1)&1 while QK
// writes slot c&1 -> the QK->PV barrier vanishes (2 barriers/chunk, was 3),
// and the QK VALU chain overlaps PV's ds_reads+MFMAs within each wave.
// K/V single-buffered: fragments reg-captured after sync A (V carried in vfp
// regs into next iteration's PV); raw barrier A2 (lgkm-only, DMAs keep flying)
// guards Ks/Vt before the c+1 DMAs re-target them. c+1 DMAs land by next
// sync A (vmcnt drain). LDS = 8+8+16 = 32768 B.
__global__ __launch_bounds__(256, 4) void attn(const unsigned short* __restrict__ QKV,
                                               const unsigned short* __restrict__ Vg,
                                               const unsigned short* __restrict__ mask16,
                                               unsigned short* __restrict__ O)
{
  __shared__ char smem[32768];
  unsigned short* Ks = (unsigned short*)smem;            // [64][64] 8 KB, xor-swizzled 16B blocks
  unsigned short* Vt = (unsigned short*)(smem + 8192);   // [64][64] 8 KB, [d][key] xor-swizzled
  unsigned short* Pb = (unsigned short*)(smem + 16384);  // [2][64][64] 16 KB P^T dbuf
  float* lsums = (float*)smem;                           // epilogue alias over dead Ks

  const int tid = threadIdx.x, wave = tid >> 6, lane = tid & 63;
  const int l16 = lane & 15, quad = lane >> 4;
  const int id = blockIdx.x;
  const int xcd = id & 7, m = id >> 3;         // round-robin XCD assumption
  const int bh = xcd * 4 + (m >> 5);           // 4 bh per XCD (K/V stay in this XCD's L2)
  const int qblk = (m & 31) * 64;
  const int b = bh >> 4, h = bh & 15;
  const unsigned short* Qg  = QKV + (size_t)b * 2048 * 3072 + h * 64;
  const unsigned short* Kg  = Qg + 1024;
  const unsigned short* Vgb = Vg + (size_t)bh * 64 * 2048;

  // per-nt bitmask row pointers: row = b*2048 + qblk + nt*16 + l16, this wave's
  // 16-key group at ushort offset c*4 + wave
  const unsigned short* mp[4];
  #pragma unroll
  for (int nt = 0; nt < 4; nt++)
    mp[nt] = mask16 + (size_t)(b*2048 + qblk + nt*16 + l16) * 128 + wave;

  // Q B-fragments resident in registers: B[n=q=l16][k=d=ks*32+quad*8+j]
  short8 qf[4][2];
  #pragma unroll
  for (int nt = 0; nt < 4; nt++)
    #pragma unroll
    for (int ks = 0; ks < 2; ks++)
      qf[nt][ks] = *(const short8*)(Qg + (size_t)(qblk + nt*16 + l16) * 3072 + ks*32 + quad*8);

  f32x4 oacc[4] = {};               // O^T strip: d = wave*16+quad*4+r, q = nt*16+l16
  float plsum[4] = {0.f, 0.f, 0.f, 0.f};
  const int sw = l16 & 7;

  // prologue: stage chunk 0; load chunk-0 mask bits
  #pragma unroll
  for (int it = 0; it < 2; it++){
    int s = it * 256 + tid;
    int row = s >> 3, bg = (s & 7) ^ (row & 7);
    stage16(Kg + (size_t)row * 3072 + bg * 8, Ks + s * 8);
    stage16(Vgb + (size_t)row * 2048 + bg * 8, Vt + s * 8);
  }
  unsigned mcur[4], mnxt[4] = {0u, 0u, 0u, 0u};
  #pragma unroll
  for (int nt = 0; nt < 4; nt++) mcur[nt] = mp[nt][0];

  short8 vfp0 = {}, vfp1 = {};      // V_c fragments carried to next iteration's PV

  for (int c = 0; c < 32; c++){
    __syncthreads();   // A: chunk-c K/V DMAs landed (vmcnt); P_{c-1} writes visible; prev PV reads done (lgkm)

    // register-capture K_c and V_c fragments (4 x b128)
    const int rbase = (wave*16 + l16) * 64;
    short8 kf0 = *(const short8*)&Ks[rbase + ((0 + quad) ^ sw) * 8];
    short8 kf1 = *(const short8*)&Ks[rbase + ((4 + quad) ^ sw) * 8];
    short8 vf0 = *(const short8*)&Vt[rbase + ((0 + quad) ^ sw) * 8];
    short8 vf1 = *(const short8*)&Vt[rbase + ((4 + quad) ^ sw) * 8];
    __asm__ volatile("s_waitcnt lgkmcnt(0)" ::: "memory");   // captures in regs (per wave)
    __builtin_amdgcn_s_barrier();                            // A2: all waves captured; no vmcnt drain
    __builtin_amdgcn_sched_barrier(0);

    // issue chunk c+1 DMAs into the (now dead) single K/V buffers + mask prefetch
    if (c < 31){
      const int nj = (c + 1) * 64;
      #pragma unroll
      for (int it = 0; it < 2; it++){
        int s = it * 256 + tid;
        int row = s >> 3, bg = (s & 7) ^ (row & 7);
        stage16(Kg + (size_t)(nj + row) * 3072 + bg * 8, Ks + s * 8);
        stage16(Vgb + (size_t)row * 2048 + nj + bg * 8, Vt + s * 8);
      }
      #pragma unroll
      for (int nt = 0; nt < 4; nt++) mnxt[nt] = mp[nt][(c + 1) * 4];
    }

    // QK_c: S^T for this wave's 16 keys; exp; mask-select 1.0; pack; P^T -> Pb[c&1]
    unsigned short* Pw = Pb + (c & 1) * 4096;
    #pragma unroll
    for (int nt = 0; nt < 4; nt++){
      f32x4 a = {0.f, 0.f, 0.f, 0.f};
      __builtin_amdgcn_s_setprio(1);
      a = __builtin_amdgcn_mfma_f32_16x16x32_bf16(kf0, qf[nt][0], a, 0, 0, 0);
      a = __builtin_amdgcn_mfma_f32_16x16x32_bf16(kf1, qf[nt][1], a, 0, 0, 0);
      __builtin_amdgcn_s_setprio(0);
      float p0 = EXP2(a[0]);
      float p1 = EXP2(a[1]);
      float p2 = EXP2(a[2]);
      float p3 = EXP2(a[3]);
      unsigned mq = mcur[nt] >> (quad << 2);
      p0 = (mq & 1u) ? p0 : 1.0f;
      p1 = (mq & 2u) ? p1 : 1.0f;
      p2 = (mq & 4u) ? p2 : 1.0f;
      p3 = (mq & 8u) ? p3 : 1.0f;
      plsum[nt] += (p0 + p1) + (p2 + p3);
      uint2 st; st.x = pack_bf16_rn(p0, p1); st.y = pack_bf16_rn(p2, p3);
      *(uint2*)&Pw[(nt*16 + l16) * 64 + ((wave*2 + (quad >> 1)) ^ sw) * 8 + (quad & 1) * 4] = st;
    }

    // PV_{c-1}: O^T strip += V_{c-1}^T * P_{c-1}^T (regs vfp*, LDS Pb[(c-1)&1])
    if (c){
      const unsigned short* Pr = Pb + ((c & 1) ^ 1) * 4096;
      #pragma unroll
      for (int kk = 0; kk < 2; kk++){
        short8 vv = kk ? vfp1 : vfp0;
        short8 pf[4];
        #pragma unroll
        for (int nt = 0; nt < 4; nt++)
          pf[nt] = *(const short8*)&Pr[(nt*16 + l16) * 64 + ((kk*4 + quad) ^ sw) * 8];
        __builtin_amdgcn_s_setprio(1);
        #pragma unroll
        for (int nt = 0; nt < 4; nt++)
          oacc[nt] = __builtin_amdgcn_mfma_f32_16x16x32_bf16(vv, pf[nt], oacc[nt], 0, 0, 0);
        __builtin_amdgcn_s_setprio(0);
      }
    }

    vfp0 = vf0; vfp1 = vf1;
    #pragma unroll
    for (int nt = 0; nt < 4; nt++) mcur[nt] = mnxt[nt];
  }

  // ---- drain: PV_31 (P in Pb[1], V_31 in vfp regs) ----
  __syncthreads();
  {
    const unsigned short* Pr = Pb + 4096;
    #pragma unroll
    for (int kk = 0; kk < 2; kk++){
      short8 vv = kk ? vfp1 : vfp0;
      short8 pf[4];
      #pragma unroll
      for (int nt = 0; nt < 4; nt++)
        pf[nt] = *(const short8*)&Pr[(nt*16 + l16) * 64 + ((kk*4 + quad) ^ sw) * 8];
      #pragma unroll
      for (int nt = 0; nt < 4; nt++)
        oacc[nt] = __builtin_amdgcn_mfma_f32_16x16x32_bf16(vv, pf[nt], oacc[nt], 0, 0, 0);
    }
  }

  // ---- epilogue: lsum cross-wave reduce via LDS; disjoint O store ----
  float lw[4];
  #pragma unroll
  for (int nt = 0; nt < 4; nt++){
    float v = plsum[nt];
    v += __shfl_xor(v, 16);
    v += __shfl_xor(v, 32);
    lw[nt] = v;
  }
  __syncthreads();                   // all waves past loop; Ks region dead -> lsums alias safe
  if (quad == 0){
    #pragma unroll
    for (int nt = 0; nt < 4; nt++) lsums[(nt*16 + l16) * 4 + wave] = lw[nt];
  }
  __syncthreads();
  float linv[4];
  #pragma unroll
  for (int nt = 0; nt < 4; nt++){
    f32x4 ls = *(const f32x4*)&lsums[(nt*16 + l16) * 4];
    linv[nt] = 1.0f / (ls[0] + ls[1] + ls[2] + ls[3]);
  }
  #pragma unroll
  for (int nt = 0; nt < 4; nt++){
    f32x4 t = oacc[nt];
    unsigned u0 = pack_bf16_rn(t[0] * linv[nt], t[1] * linv[nt]);
    unsigned u1 = pack_bf16_rn(t[2] * linv[nt], t[3] * linv[nt]);
    uint2 st; st.x = u0; st.y = u1;
    *(uint2*)&O[(size_t)(b*2048 + qblk + nt*16 + l16) * 1024 + h*64 + wave*16 + quad*4] = st;
  }
}

// ---------------- launch ----------------
extern "C" void kernel_launch(void* const* d_in, const int* in_sizes, int n_in,
                              void* d_out, int out_size, void* d_ws, size_t ws_size,
                              hipStream_t stream)
{
  const float* X  = (const float*)d_in[0];
  const int*   Mk = (const int*)d_in[1];
  const float* Wq = (const float*)d_in[2];
  const float* Wk = (const float*)d_in[3];
  const float* Wv = (const float*)d_in[4];
  const float* Wo = (const float*)d_in[5];
  float* out = (float*)d_out;

  char* ws = (char*)d_ws;
  unsigned short* Xb   = (unsigned short*)(ws + 0);          //  8 MB  [4096][1024]
  unsigned short* Wqkv = (unsigned short*)(ws + 8388608);    //  6 MB  [3072][1024]
  unsigned short* Wob  = (unsigned short*)(ws + 14680064);   //  2 MB  [1024][1024]
  unsigned short* QKV  = (unsigned short*)(ws + 16777216);   // 24 MB  [4096][3072] (V cols unused)
  unsigned short* Ob   = (unsigned short*)(ws + 41943040);   //  8 MB  [4096][1024]
  unsigned long long* Mb = (unsigned long long*)(ws + 50331648); // 1 MB [4096][32] u64 bitmask
  unsigned short* Vg   = (unsigned short*)(ws + 58720256);   //  8 MB  [32][64][2048]

  prep<<<12288, 256, 0, stream>>>(X, Mk, Wq, Wk, Wv, Wo, Xb, Wqkv, Wob, Mb);
  gemm_qkv<<<768, 256, 0, stream>>>(Xb, Wqkv, QKV, Vg);
  attn<<<1024, 256, 0, stream>>>(QKV, Vg, (const unsigned short*)Mb, Ob);
  gemm_out<<<512, 256, 0, stream>>>(Ob, Wob, out);
}

// Round 7
// 240.983 us; speedup vs baseline: 1.1132x; 1.1102x over previous
//
#include <hip/hip_runtime.h>
#include <hip/hip_bf16.h>

using short8  = __attribute__((ext_vector_type(8))) short;
using short4v = __attribute__((ext_vector_type(4))) short;
using f32x4   = __attribute__((ext_vector_type(4))) float;

#if __has_builtin(__builtin_amdgcn_exp2f)
#define EXP2(x) __builtin_amdgcn_exp2f(x)
#else
#define EXP2(x) __expf(0.6931471805599453f*(x))
#endif

__device__ __forceinline__ unsigned short f2bf(float x){
  union { float f; unsigned u; } c; c.f = x;
  unsigned u = c.u + 0x7FFFu + ((c.u >> 16) & 1u);
  return (unsigned short)(u >> 16);
}

__device__ __forceinline__ unsigned pack_bf16_rn(float a, float b){
  __hip_bfloat162 t = __float22bfloat162_rn(make_float2(a, b));
  unsigned u; __builtin_memcpy(&u, &t, 4);
  return u;
}

// ---------------- fused prep: dtype conversions + mask bit-pack (transposed) ----
// bid < 8192: bf16 conversions (X, Wq*log2e/8, Wk, Wv, Wo)
// bid in [8192,12288): mask -> 1 bit/key via ballot, TRANSPOSED layout:
// Mbits[word][row], word w covers keys w*64..w*64+63 of row (b*2048+q).
// Attn reads word c for chunk c: lanes l16 hit consecutive rows = coalesced.
__global__ __launch_bounds__(256) void prep(const float* __restrict__ X, const int* __restrict__ Mk,
                                            const float* __restrict__ Wq, const float* __restrict__ Wk,
                                            const float* __restrict__ Wv, const float* __restrict__ Wo,
                                            unsigned short* __restrict__ Xb, unsigned short* __restrict__ Wqkv,
                                            unsigned short* __restrict__ Wob, unsigned long long* __restrict__ Mbits)
{
  const int bid = blockIdx.x, tid = threadIdx.x;
  if (bid < 8192){
    const float* src; unsigned short* dst; float scale; int i;
    if (bid < 4096)      { src = X;  dst = Xb;             scale = 1.0f;          i = bid*1024 + tid*4; }
    else if (bid < 5120) { src = Wq; dst = Wqkv;           scale = 0.18033688f;   i = (bid-4096)*1024 + tid*4; } // 1/8 * log2(e)
    else if (bid < 6144) { src = Wk; dst = Wqkv + 1048576; scale = 1.0f;          i = (bid-5120)*1024 + tid*4; }
    else if (bid < 7168) { src = Wv; dst = Wqkv + 2097152; scale = 1.0f;          i = (bid-6144)*1024 + tid*4; }
    else                 { src = Wo; dst = Wob;            scale = 1.0f;          i = (bid-7168)*1024 + tid*4; }
    float4 v = *(const float4*)(src + i);
    ushort4 o;
    o.x = f2bf(v.x * scale); o.y = f2bf(v.y * scale);
    o.z = f2bf(v.z * scale); o.w = f2bf(v.w * scale);
    *(ushort4*)(dst + i) = o;
  } else {
    int row = bid - 8192;                       // 0..4095 = b*2048+q
    const int* src = Mk + (size_t)row * 2048;
    int w = tid >> 6, l = tid & 63;
    #pragma unroll
    for (int p = 0; p < 8; p++){
      int v = src[w*512 + p*64 + l];            // coalesced 256B per ballot
      unsigned long long bm = __ballot(v != 0);
      if (l == 0) Mbits[(size_t)(w*8 + p) * 4096 + row] = bm;  // [word][row]
    }
  }
}

// ---------------- async global->LDS, width 16 ----------------
__device__ __forceinline__ void stage16(const unsigned short* g, unsigned short* l){
  __builtin_amdgcn_global_load_lds(
      (const __attribute__((address_space(1))) void*)g,
      (__attribute__((address_space(3))) void*)l, 16, 0, 0);
}

// ---------------- gemm1: QKV = Xb * Wqkv^T; V-blocks write Vg transposed ----------
__global__ __launch_bounds__(256) void gemm_qkv(const unsigned short* __restrict__ A,
                                                const unsigned short* __restrict__ B,
                                                unsigned short* __restrict__ C,
                                                unsigned short* __restrict__ Vg)
{
  __shared__ unsigned short As[128*32];
  __shared__ unsigned short Bs[128*32];
  const int tid = threadIdx.x;
  const int wave = tid >> 6, lane = tid & 63, l16 = lane & 15, quad = lane >> 4;
  const int id = blockIdx.x, xcd = id & 7, m = id >> 3;
  const int bm = (m / 3) * 128, bn = (xcd * 3 + (m % 3)) * 128;
  const int wm = (wave >> 1) * 64, wn = (wave & 1) * 64;
  const int K = 1024;

  f32x4 acc[4][4] = {};
  for (int k0 = 0; k0 < K; k0 += 32){
    #pragma unroll
    for (int c = 0; c < 2; c++){
      int idx = c * 256 + tid;
      int row = idx >> 2, g = (idx & 3) * 8;
      stage16(A + (size_t)(bm + row) * K + k0 + g, &As[idx * 8]);
      stage16(B + (size_t)(bn + row) * K + k0 + g, &Bs[idx * 8]);
    }
    __syncthreads();
    short8 af[4], bf[4];
    #pragma unroll
    for (int i = 0; i < 4; i++) af[i] = *(const short8*)&As[(wm + i*16 + l16)*32 + quad*8];
    #pragma unroll
    for (int j = 0; j < 4; j++) bf[j] = *(const short8*)&Bs[(wn + j*16 + l16)*32 + quad*8];
    #pragma unroll
    for (int i = 0; i < 4; i++)
      #pragma unroll
      for (int j = 0; j < 4; j++)
        acc[i][j] = __builtin_amdgcn_mfma_f32_16x16x32_bf16(af[i], bf[j], acc[i][j], 0, 0, 0);
    __syncthreads();
  }

  if (bn < 2048){
    #pragma unroll
    for (int i = 0; i < 4; i++){
      int mrow = bm + wm + i*16 + quad*4;
      #pragma unroll
      for (int j = 0; j < 4; j++){
        int ncol = bn + wn + j*16 + l16;
        #pragma unroll
        for (int r = 0; r < 4; r++)
          C[(size_t)(mrow + r) * 3072 + ncol] = f2bf(acc[i][j][r]);
      }
    }
  } else {
    #pragma unroll
    for (int i = 0; i < 4; i++){
      int srow = bm + wm + i*16 + quad*4;
      int b = srow >> 11, s = srow & 2047;
      #pragma unroll
      for (int j = 0; j < 4; j++){
        int c = bn - 2048 + wn + j*16 + l16;
        int h = c >> 6, d = c & 63;
        ushort4 o;
        o.x = f2bf(acc[i][j][0]); o.y = f2bf(acc[i][j][1]);
        o.z = f2bf(acc[i][j][2]); o.w = f2bf(acc[i][j][3]);
        *(ushort4*)&Vg[((size_t)(b*16 + h)*64 + d) * 2048 + s] = o;
      }
    }
  }
}

// ---------------- gemm2: out = Ob * Wob^T (f32 out), 128x64 tiles, XCD-swizzled ----
__global__ __launch_bounds__(256) void gemm_out(const unsigned short* __restrict__ A,
                                                const unsigned short* __restrict__ B,
                                                float* __restrict__ Cf)
{
  __shared__ unsigned short As[128*32];
  __shared__ unsigned short Bs[64*32];
  const int tid = threadIdx.x;
  const int wave = tid >> 6, lane = tid & 63, l16 = lane & 15, quad = lane >> 4;
  const int id = blockIdx.x, xcd = id & 7, m = id >> 3;
  const int bm = (m >> 1) * 128, bn = (xcd * 2 + (m & 1)) * 64;
  const int wm = (wave >> 1) * 64, wn = (wave & 1) * 32;
  const int K = 1024, N = 1024;

  f32x4 acc[4][2] = {};
  for (int k0 = 0; k0 < K; k0 += 32){
    #pragma unroll
    for (int c = 0; c < 2; c++){
      int idx = c * 256 + tid;
      int row = idx >> 2, g = (idx & 3) * 8;
      stage16(A + (size_t)(bm + row) * K + k0 + g, &As[idx * 8]);
    }
    stage16(B + (size_t)(bn + (tid >> 2)) * K + k0 + (tid & 3) * 8, &Bs[tid * 8]);
    __syncthreads();
    short8 af[4], bf[2];
    #pragma unroll
    for (int i = 0; i < 4; i++) af[i] = *(const short8*)&As[(wm + i*16 + l16)*32 + quad*8];
    #pragma unroll
    for (int j = 0; j < 2; j++) bf[j] = *(const short8*)&Bs[(wn + j*16 + l16)*32 + quad*8];
    #pragma unroll
    for (int i = 0; i < 4; i++)
      #pragma unroll
      for (int j = 0; j < 2; j++)
        acc[i][j] = __builtin_amdgcn_mfma_f32_16x16x32_bf16(af[i], bf[j], acc[i][j], 0, 0, 0);
    __syncthreads();
  }
  #pragma unroll
  for (int i = 0; i < 4; i++){
    int mrow = bm + wm + i*16 + quad*4;
    #pragma unroll
    for (int j = 0; j < 2; j++){
      int ncol = bn + wn + j*16 + l16;
      #pragma unroll
      for (int r = 0; r < 4; r++)
        Cf[(size_t)(mrow + r) * N + ncol] = acc[i][j][r];
    }
  }
}

// ---------------- attention: wave-autonomous, P stays in registers -------------
// Rounds 2-6: wall invariant (~100us) under issue reduction, residency, LDS and
// barrier-structure changes -> the 4-wave d-strip decomposition's cross-wave P
// exchange (LDS round-trip + intra-chunk barriers, phase-locked waves) IS the wall.
// This version: each wave owns 16 q-rows end-to-end. Key identity: S^T MFMA
// output (lane l16 holds S^T[key=quad*4+r][q=l16]) IS the _1k PV A-operand
// layout A[m=q=l16][k=key=quad*4+j] -> P never leaves registers. PV computes
// O[q][d] = mfma(A=P, B=V^T-frag) with K=16 (operand layouts HW-verified by
// round-0's passing kernel). No cross-wave data flow; lsum reduced by shfl only.
// One __syncthreads per chunk (K/V double-buffer handoff). LDS 32 KB.
__global__ __launch_bounds__(256, 4) void attn(const unsigned short* __restrict__ QKV,
                                               const unsigned short* __restrict__ Vg,
                                               const unsigned long long* __restrict__ Mb,
                                               unsigned short* __restrict__ O)
{
  __shared__ char smem[32768];
  unsigned short* Ks = (unsigned short*)smem;            // [2][64][64] xor-swizzled 16B blocks
  unsigned short* Vt = (unsigned short*)(smem + 16384);  // [2][64][64] [d][key] xor-swizzled

  const int tid = threadIdx.x, wave = tid >> 6, lane = tid & 63;
  const int l16 = lane & 15, quad = lane >> 4;
  const int id = blockIdx.x;
  const int xcd = id & 7, m = id >> 3;         // round-robin XCD assumption
  const int bh = xcd * 4 + (m >> 5);           // 4 bh per XCD (K/V stay in this XCD's L2)
  const int qblk = (m & 31) * 64;
  const int b = bh >> 4, h = bh & 15;
  const unsigned short* Qg  = QKV + (size_t)b * 2048 * 3072 + h * 64;
  const unsigned short* Kg  = Qg + 1024;
  const unsigned short* Vgb = Vg + (size_t)bh * 64 * 2048;

  const int qrow = qblk + wave*16 + l16;       // this lane's q (B-frag row, lsum owner)
  const unsigned long long* mrow = Mb + (size_t)b*2048 + qrow;   // + c*4096 per chunk

  // Q B-fragment: B[n=q=l16][k=d=ks*32+quad*8+j]
  short8 qf0 = *(const short8*)(Qg + (size_t)qrow * 3072 + quad*8);
  short8 qf1 = *(const short8*)(Qg + (size_t)qrow * 3072 + 32 + quad*8);

  f32x4 oacc[4] = {};               // O[q=quad*4+r][d=ng*16+l16]
  float plsum = 0.f;                // keys of this lane's quads, q = l16
  const int sw = l16 & 7;

  // prologue: stage chunk 0 into buffer 0; chunk-0 mask word
  #pragma unroll
  for (int it = 0; it < 2; it++){
    int s = it * 256 + tid;
    int row = s >> 3, bg = (s & 7) ^ (row & 7);
    stage16(Kg + (size_t)row * 3072 + bg * 8, Ks + s * 8);
    stage16(Vgb + (size_t)row * 2048 + bg * 8, Vt + s * 8);
  }
  unsigned long long mcur = mrow[0], mnxt = 0ull;

  for (int c = 0; c < 32; c++){
    const int buf = (c & 1) * 4096;
    __syncthreads();   // chunk-c DMAs landed (vmcnt); all waves done reading buf^1 (chunk c-1)

    // issue chunk c+1 DMAs into the other buffer; they fly through the whole body
    if (c < 31){
      const int nj = (c + 1) * 64, nbuf = ((c + 1) & 1) * 4096;
      #pragma unroll
      for (int it = 0; it < 2; it++){
        int s = it * 256 + tid;
        int row = s >> 3, bg = (s & 7) ^ (row & 7);
        stage16(Kg + (size_t)(nj + row) * 3072 + bg * 8, Ks + nbuf + s * 8);
        stage16(Vgb + (size_t)row * 2048 + nj + bg * 8, Vt + nbuf + s * 8);
      }
      mnxt = mrow[(size_t)(c + 1) * 4096];
    }

    // fully wave-private: 4 key-blocks of 16; per kb: QK -> exp -> in-reg P -> PV
    #pragma unroll
    for (int kb = 0; kb < 4; kb++){
      const int krow = kb*16 + l16;           // A[m=key] row in Ks
      short8 kf0 = *(const short8*)&Ks[buf + krow*64 + ((0 + quad) ^ sw) * 8];
      short8 kf1 = *(const short8*)&Ks[buf + krow*64 + ((4 + quad) ^ sw) * 8];
      f32x4 a = {0.f, 0.f, 0.f, 0.f};
      __builtin_amdgcn_s_setprio(1);
      a = __builtin_amdgcn_mfma_f32_16x16x32_bf16(kf0, qf0, a, 0, 0, 0);
      a = __builtin_amdgcn_mfma_f32_16x16x32_bf16(kf1, qf1, a, 0, 0, 0);
      __builtin_amdgcn_s_setprio(0);
      // S^T[key=quad*4+r][q=l16]; log2 domain (log2e folded into Wq); masked -> 1.0
      unsigned mm = (unsigned)(mcur >> (kb*16 + quad*4)) & 15u;
      float p0 = EXP2(a[0]); p0 = (mm & 1u) ? p0 : 1.0f;
      float p1 = EXP2(a[1]); p1 = (mm & 2u) ? p1 : 1.0f;
      float p2 = EXP2(a[2]); p2 = (mm & 4u) ? p2 : 1.0f;
      float p3 = EXP2(a[3]); p3 = (mm & 8u) ? p3 : 1.0f;
      plsum += (p0 + p1) + (p2 + p3);
      uint2 pu; pu.x = pack_bf16_rn(p0, p1); pu.y = pack_bf16_rn(p2, p3);
      short4v pa = *(short4v*)&pu;            // A[m=q=l16][k=key=quad*4+j] == S^T regs
      __builtin_amdgcn_s_setprio(1);
      #pragma unroll
      for (int ng = 0; ng < 4; ng++){
        const int vrow = ng*16 + l16;         // B[n=d] row in Vt
        short4v vf = *(const short4v*)&Vt[buf + vrow*64 +
                       ((kb*2 + (quad >> 1)) ^ sw) * 8 + (quad & 1) * 4];
        oacc[ng] = __builtin_amdgcn_mfma_f32_16x16x16bf16_1k(pa, vf, oacc[ng], 0, 0, 0);
      }
      __builtin_amdgcn_s_setprio(0);
    }
    mcur = mnxt;
  }

  // ---- epilogue: shfl-only lsum reduce; scale; direct store (no LDS, no sync) ----
  float v = plsum;
  v += __shfl_xor(v, 16);
  v += __shfl_xor(v, 32);
  float linv = 1.0f / v;                      // total for q = l16
  float lr[4];
  #pragma unroll
  for (int r = 0; r < 4; r++) lr[r] = __shfl(linv, quad*4 + r);   // for q = quad*4+r

  unsigned short* Ob = O + (size_t)(b*2048 + qblk + wave*16) * 1024 + h*64;
  #pragma unroll
  for (int ng = 0; ng < 4; ng++)
    #pragma unroll
    for (int r = 0; r < 4; r++)
      Ob[(size_t)(quad*4 + r) * 1024 + ng*16 + l16] = f2bf(oacc[ng][r] * lr[r]);
}

// ---------------- launch ----------------
extern "C" void kernel_launch(void* const* d_in, const int* in_sizes, int n_in,
                              void* d_out, int out_size, void* d_ws, size_t ws_size,
                              hipStream_t stream)
{
  const float* X  = (const float*)d_in[0];
  const int*   Mk = (const int*)d_in[1];
  const float* Wq = (const float*)d_in[2];
  const float* Wk = (const float*)d_in[3];
  const float* Wv = (const float*)d_in[4];
  const float* Wo = (const float*)d_in[5];
  float* out = (float*)d_out;

  char* ws = (char*)d_ws;
  unsigned short* Xb   = (unsigned short*)(ws + 0);          //  8 MB  [4096][1024]
  unsigned short* Wqkv = (unsigned short*)(ws + 8388608);    //  6 MB  [3072][1024]
  unsigned short* Wob  = (unsigned short*)(ws + 14680064);   //  2 MB  [1024][1024]
  unsigned short* QKV  = (unsigned short*)(ws + 16777216);   // 24 MB  [4096][3072] (V cols unused)
  unsigned short* Ob   = (unsigned short*)(ws + 41943040);   //  8 MB  [4096][1024]
  unsigned long long* Mb = (unsigned long long*)(ws + 50331648); // 1 MB [32 words][4096 rows]
  unsigned short* Vg   = (unsigned short*)(ws + 58720256);   //  8 MB  [32][64][2048]

  prep<<<12288, 256, 0, stream>>>(X, Mk, Wq, Wk, Wv, Wo, Xb, Wqkv, Wob, Mb);
  gemm_qkv<<<768, 256, 0, stream>>>(Xb, Wqkv, QKV, Vg);
  attn<<<1024, 256, 0, stream>>>(QKV, Vg, Mb, Ob);
  gemm_out<<<512, 256, 0, stream>>>(Ob, Wob, out);
}